// Round 5
// baseline (173.376 us; speedup 1.0000x reference)
//
#include <hip/hip_runtime.h>
#include <hip/hip_bf16.h>
#include <hip/hip_cooperative_groups.h>
#include <math.h>

namespace cg = cooperative_groups;

#define H 128
#define NB 8
#define NVN 1024   // virtual nodes per batch
#define MLIG 64    // ligand atoms per batch
#define J 64       // H/2

typedef _Float16 f16;
typedef __attribute__((ext_vector_type(8))) _Float16 f16x8;
typedef __attribute__((ext_vector_type(4))) _Float16 f16x4;
typedef __attribute__((ext_vector_type(4))) float f32x4;

__device__ __forceinline__ f16x8 relu8(f16x8 x) {
    f16x8 z;
    #pragma unroll
    for (int i = 0; i < 8; ++i) z[i] = x[i] > (_Float16)0 ? x[i] : (_Float16)0;
    return z;
}

// One fused cooperative kernel: 256 blocks x 512 threads (1 block/CU).
// Phase A: fold projection weights (Wc = W @ W1-half, biases).
// Phase B: project embeddings -> f16 v_h / l_h (2x 32-row tiles per block).
// Phase C: per (b,m) pairwise MLP via MFMA + softmax + coords einsum.
__global__ __launch_bounds__(512) void fused_pair_attn(
    const float* __restrict__ VE, const float* __restrict__ vc,
    const float* __restrict__ LE,
    const float* __restrict__ Wv, const float* __restrict__ bv,
    const float* __restrict__ Wl, const float* __restrict__ bl,
    const float* __restrict__ W1, const float* __restrict__ b1,
    const float* __restrict__ W2, const float* __restrict__ b2,
    const float* __restrict__ W3,
    float* __restrict__ Wc_v, float* __restrict__ Wc_l,
    float* __restrict__ bias_v, float* __restrict__ bias_l,
    f16* __restrict__ v_h, f16* __restrict__ l_h,
    float* __restrict__ out_coords, float* __restrict__ out_attn)
{
    __shared__ union __align__(16) {
        struct { float part[512], partb[512]; } a;
        struct { float Xs[2][32][132]; } b;
        struct {
            f16   Xs[64 * 136];
            float zrow[2][NVN];
            float redm[2][4], reds[2][4], redc[2][3][4];
        } c;
    } sm;

    cg::grid_group grid = cg::this_grid();
    const int tid = threadIdx.x;
    const int bid = blockIdx.x;

    // ================= Phase A: combine weights =================
    {
        const int o   = tid & 127;
        const int kq  = tid >> 7;          // 0..3, 32 k's each
        const int d   = bid & 127;
        const int mat = bid >> 7;

        const float* Wsrc = (mat == 0) ? Wv : Wl;
        const float* W1p  = (mat == 0) ? (W1 + H * H) : W1;
        const float* bsrc = (mat == 0) ? bv : bl;
        float* dst        = (mat == 0) ? Wc_v : Wc_l;

        float acc = 0.f, accb = 0.f;
        #pragma unroll 8
        for (int k = kq * 32; k < kq * 32 + 32; ++k) {
            float w = W1p[k * H + o];
            acc  += Wsrc[d * H + k] * w;
            accb += bsrc[k] * w;
        }
        sm.a.part[tid]  = acc;
        sm.a.partb[tid] = accb;
        __syncthreads();

        if (kq == 0) {
            dst[d * H + o] = sm.a.part[o] + sm.a.part[o + 128]
                           + sm.a.part[o + 256] + sm.a.part[o + 384];
            if (d == 0) {
                float bb = sm.a.partb[o] + sm.a.partb[o + 128]
                         + sm.a.partb[o + 256] + sm.a.partb[o + 384];
                if (mat == 0) bias_v[o] = bb;
                else          bias_l[o] = bb + b1[o];
            }
        }
    }
    __threadfence();
    grid.sync();

    // ================= Phase B: projections (f16 out) =================
    // 272 tiles of 32 rows: tiles 0..255 virtual, 256..271 ligand.
    // Blocks 0..135 each handle 2 tiles (sub = tid>>8).
    if (bid < 136) {
        const int sub = tid >> 8;
        const int ts  = tid & 255;
        const int t   = bid * 2 + sub;

        const float* src; const float* Wc; const float* bias; f16* dst; int r0;
        if (t < 256) { src = VE; Wc = Wc_v; bias = bias_v; dst = v_h; r0 = t * 32; }
        else         { src = LE; Wc = Wc_l; bias = bias_l; dst = l_h; r0 = (t - 256) * 32; }

        #pragma unroll
        for (int i = 0; i < 4; ++i) {
            int idx = ts + i * 256;
            int r = idx >> 5, cg2 = idx & 31;
            *(f32x4*)&sm.b.Xs[sub][r][cg2 * 4] =
                *(const f32x4*)&src[(size_t)(r0 + r) * H + cg2 * 4];
        }
        __syncthreads();

        const int rt = (ts >> 5) * 4;
        const int c0 = (ts & 31) * 4;

        f32x4 bb = *(const f32x4*)&bias[c0];
        f32x4 acc[4];
        #pragma unroll
        for (int i = 0; i < 4; ++i) acc[i] = bb;

        #pragma unroll 4
        for (int k4 = 0; k4 < 32; ++k4) {
            f32x4 xr[4];
            #pragma unroll
            for (int i = 0; i < 4; ++i) xr[i] = *(const f32x4*)&sm.b.Xs[sub][rt + i][k4 * 4];
            f32x4 w0 = *(const f32x4*)&Wc[(size_t)(k4 * 4 + 0) * H + c0];
            f32x4 w1 = *(const f32x4*)&Wc[(size_t)(k4 * 4 + 1) * H + c0];
            f32x4 w2 = *(const f32x4*)&Wc[(size_t)(k4 * 4 + 2) * H + c0];
            f32x4 w3 = *(const f32x4*)&Wc[(size_t)(k4 * 4 + 3) * H + c0];
            #pragma unroll
            for (int i = 0; i < 4; ++i) {
                acc[i] += xr[i][0] * w0;
                acc[i] += xr[i][1] * w1;
                acc[i] += xr[i][2] * w2;
                acc[i] += xr[i][3] * w3;
            }
        }

        #pragma unroll
        for (int i = 0; i < 4; ++i) {
            f16x4 hv;
            hv[0] = (f16)acc[i][0]; hv[1] = (f16)acc[i][1];
            hv[2] = (f16)acc[i][2]; hv[3] = (f16)acc[i][3];
            *(f16x4*)&dst[(size_t)(r0 + rt + i) * H + c0] = hv;
        }
    }
    __threadfence();
    grid.sync();

    // ================= Phase C: pairwise MLP + softmax + coords =================
    {
        const int bm0  = bid * 2;
        const int b    = bm0 >> 6;
        const int w    = tid >> 6;         // 0..7
        const int mi   = w >> 2;           // which m
        const int wl   = w & 3;            // n-stripe within m
        const int lane = tid & 63;
        const int g    = lane >> 4;
        const int c    = lane & 15;
        const int bm   = bm0 + mi;

        f16x8 bw[4][4];
        #pragma unroll
        for (int ks = 0; ks < 4; ++ks)
            #pragma unroll
            for (int fj = 0; fj < 4; ++fj) {
                f16x8 f;
                #pragma unroll
                for (int e = 0; e < 8; ++e)
                    f[e] = (f16)W2[(ks * 32 + g * 8 + e) * J + fj * 16 + c];
                bw[ks][fj] = f;
            }

        f16x8 lp[4];
        #pragma unroll
        for (int ks = 0; ks < 4; ++ks)
            lp[ks] = *(const f16x8*)&l_h[(size_t)bm * H + ks * 32 + g * 8];

        float b2r[4], w3r[4];
        #pragma unroll
        for (int fj = 0; fj < 4; ++fj) {
            b2r[fj] = b2[fj * 16 + c];
            w3r[fj] = W3[fj * 16 + c];
        }

        const f16* vsrc = v_h + (size_t)b * NVN * H;

        f16x8 st0 = *(const f16x8*)&vsrc[(size_t)tid * 8];
        f16x8 st1 = *(const f16x8*)&vsrc[(size_t)(tid + 512) * 8];

        const int wr0 = (tid >> 4) * 136 + (tid & 15) * 8;
        const int wr1 = ((tid + 512) >> 4) * 136 + (tid & 15) * 8;
        const int rdbase = (wl * 16 + c) * 136 + g * 8;

        for (int ch = 0; ch < 16; ++ch) {
            *(f16x8*)&sm.c.Xs[wr0] = st0;
            *(f16x8*)&sm.c.Xs[wr1] = st1;
            __syncthreads();

            if (ch < 15) {
                const f16* p = vsrc + (size_t)(ch + 1) * 64 * H;
                st0 = *(const f16x8*)&p[(size_t)tid * 8];
                st1 = *(const f16x8*)&p[(size_t)(tid + 512) * 8];
            }

            f32x4 acc[4];
            #pragma unroll
            for (int fj = 0; fj < 4; ++fj) acc[fj] = (f32x4){0.f, 0.f, 0.f, 0.f};

            #pragma unroll
            for (int ks = 0; ks < 4; ++ks) {
                f16x8 xv = *(const f16x8*)&sm.c.Xs[rdbase + ks * 32];
                f16x8 af = relu8(xv + lp[ks]);
                #pragma unroll
                for (int fj = 0; fj < 4; ++fj)
                    acc[fj] = __builtin_amdgcn_mfma_f32_16x16x32_f16(
                        af, bw[ks][fj], acc[fj], 0, 0, 0);
            }

            float pz[4];
            #pragma unroll
            for (int r = 0; r < 4; ++r) {
                float s = fmaxf(acc[0][r] + b2r[0], 0.f) * w3r[0]
                        + fmaxf(acc[1][r] + b2r[1], 0.f) * w3r[1]
                        + fmaxf(acc[2][r] + b2r[2], 0.f) * w3r[2]
                        + fmaxf(acc[3][r] + b2r[3], 0.f) * w3r[3];
                s += __shfl_xor(s, 1);
                s += __shfl_xor(s, 2);
                s += __shfl_xor(s, 4);
                s += __shfl_xor(s, 8);
                pz[r] = s;
            }
            if (c < 4) {
                float zv = (c == 0) ? pz[0] : (c == 1) ? pz[1] : (c == 2) ? pz[2] : pz[3];
                sm.c.zrow[mi][ch * 64 + wl * 16 + g * 4 + c] = zv;
            }
            __syncthreads();
        }

        // per-m softmax + coords
        const int t2 = tid & 255;
        const int mg = tid >> 8;
        const int wg = (tid >> 6) & 3;
        const int lane2 = tid & 63;

        float zloc[4];
        float mx = -INFINITY;
        #pragma unroll
        for (int k = 0; k < 4; ++k) {
            zloc[k] = sm.c.zrow[mg][t2 + k * 256];
            mx = fmaxf(mx, zloc[k]);
        }
        #pragma unroll
        for (int off = 32; off > 0; off >>= 1) mx = fmaxf(mx, __shfl_xor(mx, off));
        if (lane2 == 0) sm.c.redm[mg][wg] = mx;
        __syncthreads();
        if (t2 == 0)
            sm.c.redm[mg][0] = fmaxf(fmaxf(sm.c.redm[mg][0], sm.c.redm[mg][1]),
                                     fmaxf(sm.c.redm[mg][2], sm.c.redm[mg][3]));
        __syncthreads();
        const float gmax = sm.c.redm[mg][0];

        float s = 0.f;
        #pragma unroll
        for (int k = 0; k < 4; ++k) {
            zloc[k] = expf(zloc[k] - gmax);
            s += zloc[k];
        }
        #pragma unroll
        for (int off = 32; off > 0; off >>= 1) s += __shfl_xor(s, off);
        if (lane2 == 0) sm.c.reds[mg][wg] = s;
        __syncthreads();
        if (t2 == 0) sm.c.reds[mg][0] = sm.c.reds[mg][0] + sm.c.reds[mg][1]
                                      + sm.c.reds[mg][2] + sm.c.reds[mg][3];
        __syncthreads();
        const float inv = 1.f / sm.c.reds[mg][0];

        float cx = 0.f, cy = 0.f, cz = 0.f;
        #pragma unroll
        for (int k = 0; k < 4; ++k) {
            int n = t2 + k * 256;
            float a = zloc[k] * inv;
            out_attn[(size_t)(bm0 + mg) * NVN + n] = a;
            const float* vcp = vc + (size_t)(b * NVN + n) * 3;
            cx += a * vcp[0];
            cy += a * vcp[1];
            cz += a * vcp[2];
        }
        #pragma unroll
        for (int off = 32; off > 0; off >>= 1) {
            cx += __shfl_xor(cx, off);
            cy += __shfl_xor(cy, off);
            cz += __shfl_xor(cz, off);
        }
        if (lane2 == 0) {
            sm.c.redc[mg][0][wg] = cx;
            sm.c.redc[mg][1][wg] = cy;
            sm.c.redc[mg][2][wg] = cz;
        }
        __syncthreads();
        if (t2 == 0) {
            const int o = (bm0 + mg) * 3;
            out_coords[o + 0] = sm.c.redc[mg][0][0] + sm.c.redc[mg][0][1]
                              + sm.c.redc[mg][0][2] + sm.c.redc[mg][0][3];
            out_coords[o + 1] = sm.c.redc[mg][1][0] + sm.c.redc[mg][1][1]
                              + sm.c.redc[mg][1][2] + sm.c.redc[mg][1][3];
            out_coords[o + 2] = sm.c.redc[mg][2][0] + sm.c.redc[mg][2][1]
                              + sm.c.redc[mg][2][2] + sm.c.redc[mg][2][3];
        }
    }
}

// -------------------------------------------------------------------------
extern "C" void kernel_launch(void* const* d_in, const int* in_sizes, int n_in,
                              void* d_out, int out_size, void* d_ws, size_t ws_size,
                              hipStream_t stream)
{
    const float* VE = (const float*)d_in[0];   // [8192, 128]
    const float* vc = (const float*)d_in[1];   // [8192, 3]
    const float* LE = (const float*)d_in[2];   // [512, 128]
    const float* Wv = (const float*)d_in[6];
    const float* bv = (const float*)d_in[7];
    const float* Wl = (const float*)d_in[8];
    const float* bl = (const float*)d_in[9];
    const float* W1 = (const float*)d_in[10];
    const float* b1 = (const float*)d_in[11];
    const float* W2 = (const float*)d_in[12];
    const float* b2 = (const float*)d_in[13];
    const float* W3 = (const float*)d_in[14];
    // b3 cancels in softmax

    float* ws     = (float*)d_ws;
    float* Wc_v   = ws;                        // 16384 fp32
    float* Wc_l   = ws + 16384;                // 16384
    float* bias_v = ws + 32768;                // 128
    float* bias_l = ws + 32896;                // 128
    f16*   v_hp   = (f16*)(ws + 33024);        // 8192*128 f16
    f16*   l_hp   = v_hp + (size_t)NB * NVN * H;  // 512*128 f16

    float* out_coords = (float*)d_out;         // [512, 3]
    float* out_attn   = out_coords + NB * MLIG * 3;

    void* args[] = {
        (void*)&VE, (void*)&vc, (void*)&LE,
        (void*)&Wv, (void*)&bv, (void*)&Wl, (void*)&bl,
        (void*)&W1, (void*)&b1, (void*)&W2, (void*)&b2, (void*)&W3,
        (void*)&Wc_v, (void*)&Wc_l, (void*)&bias_v, (void*)&bias_l,
        (void*)&v_hp, (void*)&l_hp,
        (void*)&out_coords, (void*)&out_attn,
    };
    hipLaunchCooperativeKernel((void*)fused_pair_attn,
                               dim3(NB * MLIG / 2), dim3(512),
                               args, 0, stream);
}

// Round 6
// 57.093 us; speedup vs baseline: 3.0367x; 3.0367x over previous
//
#include <hip/hip_runtime.h>
#include <hip/hip_bf16.h>
#include <math.h>

#define H 128
#define NB 8
#define NVN 1024   // virtual nodes per batch
#define MLIG 64    // ligand atoms per batch
#define J 64       // H/2

typedef _Float16 f16;
typedef __attribute__((ext_vector_type(8))) _Float16 f16x8;
typedef __attribute__((ext_vector_type(4))) _Float16 f16x4;
typedef __attribute__((ext_vector_type(4))) float f32x4;

__device__ __forceinline__ f16x8 relu8(f16x8 x) {
    f16x8 z;
    #pragma unroll
    for (int i = 0; i < 8; ++i) z[i] = x[i] > (_Float16)0 ? x[i] : (_Float16)0;
    return z;
}

// Butterfly add over the 16-lane row via DPP (pure VALU, no LDS pipe).
// ctrl: 0xB1 = quad_perm xor1, 0x4E = quad_perm xor2,
//       0x141 = row_half_mirror (xor4), 0x140 = row_mirror (xor8).
template <int CTRL>
__device__ __forceinline__ float dpp_add(float x) {
    union { float f; int i; } u, r;
    u.f = x;
    r.i = __builtin_amdgcn_update_dpp(0, u.i, CTRL, 0xf, 0xf, true);
    return x + r.f;
}
__device__ __forceinline__ float row16_sum(float x) {
    x = dpp_add<0xB1>(x);
    x = dpp_add<0x4E>(x);
    x = dpp_add<0x141>(x);
    x = dpp_add<0x140>(x);
    return x;
}

// -------------------------------------------------------------------------
// Kernel 1: fold the two projection layers into combined weights.
// -------------------------------------------------------------------------
__global__ __launch_bounds__(256) void combine_weights2(
    const float* __restrict__ Wv, const float* __restrict__ bv,
    const float* __restrict__ Wl, const float* __restrict__ bl,
    const float* __restrict__ W1, const float* __restrict__ b1,
    float* __restrict__ Wc_v, float* __restrict__ Wc_l,
    float* __restrict__ bias_v, float* __restrict__ bias_l)
{
    __shared__ float part[256];
    __shared__ float partb[256];
    const int tid = threadIdx.x;
    const int o   = tid & 127;
    const int kh  = tid >> 7;
    const int d   = blockIdx.x;
    const int mat = blockIdx.y;

    const float* Wsrc = (mat == 0) ? Wv : Wl;
    const float* W1p  = (mat == 0) ? (W1 + H * H) : W1;
    const float* bsrc = (mat == 0) ? bv : bl;
    float* dst        = (mat == 0) ? Wc_v : Wc_l;

    float acc = 0.f, accb = 0.f;
    #pragma unroll 8
    for (int k = kh * 64; k < kh * 64 + 64; ++k) {
        float w = W1p[k * H + o];
        acc  += Wsrc[d * H + k] * w;
        accb += bsrc[k] * w;
    }
    part[tid]  = acc;
    partb[tid] = accb;
    __syncthreads();

    if (kh == 0) {
        dst[d * H + o] = part[o] + part[o + 128];
        if (d == 0) {
            float bb = partb[o] + partb[o + 128];
            if (mat == 0) bias_v[o] = bb;
            else          bias_l[o] = bb + b1[o];
        }
    }
}

// -------------------------------------------------------------------------
// Kernel 2: projections as register-tiled fp32 GEMM, f16 output.
// -------------------------------------------------------------------------
__global__ __launch_bounds__(256) void project2(
    const float* __restrict__ VE, const float* __restrict__ LE,
    const float* __restrict__ Wc_v, const float* __restrict__ Wc_l,
    const float* __restrict__ bias_v, const float* __restrict__ bias_l,
    f16* __restrict__ v_h, f16* __restrict__ l_h)
{
    __shared__ float Xs[32][132];
    const int bid = blockIdx.x;
    const int tid = threadIdx.x;

    const float* src; const float* Wc; const float* bias; f16* dst; int r0;
    if (bid < 256) { src = VE; Wc = Wc_v; bias = bias_v; dst = v_h; r0 = bid * 32; }
    else           { src = LE; Wc = Wc_l; bias = bias_l; dst = l_h; r0 = (bid - 256) * 32; }

    #pragma unroll
    for (int i = 0; i < 4; ++i) {
        int idx = tid + i * 256;
        int r = idx >> 5, cg = idx & 31;
        *(f32x4*)&Xs[r][cg * 4] = *(const f32x4*)&src[(size_t)(r0 + r) * H + cg * 4];
    }
    __syncthreads();

    const int rt = (tid >> 5) * 4;
    const int c0 = (tid & 31) * 4;

    f32x4 bb = *(const f32x4*)&bias[c0];
    f32x4 acc[4];
    #pragma unroll
    for (int i = 0; i < 4; ++i) acc[i] = bb;

    #pragma unroll 4
    for (int k4 = 0; k4 < 32; ++k4) {
        f32x4 xr[4];
        #pragma unroll
        for (int i = 0; i < 4; ++i) xr[i] = *(const f32x4*)&Xs[rt + i][k4 * 4];
        f32x4 w0 = *(const f32x4*)&Wc[(size_t)(k4 * 4 + 0) * H + c0];
        f32x4 w1 = *(const f32x4*)&Wc[(size_t)(k4 * 4 + 1) * H + c0];
        f32x4 w2 = *(const f32x4*)&Wc[(size_t)(k4 * 4 + 2) * H + c0];
        f32x4 w3 = *(const f32x4*)&Wc[(size_t)(k4 * 4 + 3) * H + c0];
        #pragma unroll
        for (int i = 0; i < 4; ++i) {
            acc[i] += xr[i][0] * w0;
            acc[i] += xr[i][1] * w1;
            acc[i] += xr[i][2] * w2;
            acc[i] += xr[i][3] * w3;
        }
    }

    #pragma unroll
    for (int i = 0; i < 4; ++i) {
        f16x4 hv;
        hv[0] = (f16)acc[i][0]; hv[1] = (f16)acc[i][1];
        hv[2] = (f16)acc[i][2]; hv[3] = (f16)acc[i][3];
        *(f16x4*)&dst[(size_t)(r0 + rt + i) * H + c0] = hv;
    }
}

// -------------------------------------------------------------------------
// Kernel 3: pairwise MLP -> z only. Grid 512 (2 blocks/CU): block = (pair
// of m's, half of n-range). 512 thr; waves 0-3 -> m0, 4-7 -> m1; 8 chunks
// of 64 n. LDS double-buffered + XOR-swizzled (conflict-free b128), ONE
// barrier per chunk. Layer-3 reduce via DPP (VALU, no LDS pipe).
// z written straight to global zbuf; softmax in kernel 4.
// -------------------------------------------------------------------------
__global__ __launch_bounds__(512) void pair_mlp(
    const f16* __restrict__ v_h, const f16* __restrict__ l_h,
    const float* __restrict__ W2, const float* __restrict__ b2,
    const float* __restrict__ W3, float* __restrict__ zbuf)
{
    __shared__ f16 Xs[2][64 * 128];    // 32 KB, XOR-swizzled

    // XCD swizzle: bid%8 = XCD -> wg so that each XCD owns one batch.
    const int bid = blockIdx.x;
    const int wg  = (bid & 7) * 64 + (bid >> 3);
    const int half = wg & 1;           // n-half
    const int pair = wg >> 1;          // 0..255
    const int bm0  = pair * 2;
    const int b    = bm0 >> 6;

    const int tid  = threadIdx.x;
    const int w    = tid >> 6;         // 0..7
    const int mi   = w >> 2;
    const int wl   = w & 3;            // 16-row stripe within 64-row chunk
    const int lane = tid & 63;
    const int g    = lane >> 4;
    const int c    = lane & 15;
    const int bm   = bm0 + mi;

    // W2 fragments (f16) in registers
    f16x8 bw[4][4];
    #pragma unroll
    for (int ks = 0; ks < 4; ++ks)
        #pragma unroll
        for (int fj = 0; fj < 4; ++fj) {
            f16x8 f;
            #pragma unroll
            for (int e = 0; e < 8; ++e)
                f[e] = (f16)W2[(ks * 32 + g * 8 + e) * J + fj * 16 + c];
            bw[ks][fj] = f;
        }

    f16x8 lp[4];
    #pragma unroll
    for (int ks = 0; ks < 4; ++ks)
        lp[ks] = *(const f16x8*)&l_h[(size_t)bm * H + ks * 32 + g * 8];

    float b2r[4], w3r[4];
    #pragma unroll
    for (int fj = 0; fj < 4; ++fj) {
        b2r[fj] = b2[fj * 16 + c];
        w3r[fj] = W3[fj * 16 + c];
    }

    // chunk rows: n0(ch) = half*512 + ch*64
    const f16* vsrc = v_h + ((size_t)b * NVN + half * 512) * H;

    // LDS write offsets (XOR swizzle: chunk ^= row&7, 16B chunks)
    const int wrow = tid >> 4;                       // 0..31
    const int wchk = (tid & 15) ^ (wrow & 7);
    const int wr0  = wrow * 128 + wchk * 8;
    const int wr1  = wr0 + 32 * 128;                 // rows 32..63, same XOR
    // LDS read offsets: row = wl*16+c, chunk(ks) = (ks*4+g) ^ (c&7)
    const int rrow = (wl * 16 + c) * 128;
    const int rx   = c & 7;

    // prologue: load chunk 0
    f16x8 st0 = *(const f16x8*)&vsrc[(size_t)tid * 8];
    f16x8 st1 = *(const f16x8*)&vsrc[(size_t)(tid + 512) * 8];

    float* zdst = zbuf + (size_t)bm0 * NVN + half * 512;

    for (int ch = 0; ch < 8; ++ch) {
        f16* buf = Xs[ch & 1];
        *(f16x8*)&buf[wr0] = st0;
        *(f16x8*)&buf[wr1] = st1;
        __syncthreads();

        if (ch < 7) {
            const f16* p = vsrc + (size_t)(ch + 1) * 64 * H;
            st0 = *(const f16x8*)&p[(size_t)tid * 8];
            st1 = *(const f16x8*)&p[(size_t)(tid + 512) * 8];
        }

        f32x4 acc[4];
        #pragma unroll
        for (int fj = 0; fj < 4; ++fj) acc[fj] = (f32x4){0.f, 0.f, 0.f, 0.f};

        #pragma unroll
        for (int ks = 0; ks < 4; ++ks) {
            f16x8 xv = *(const f16x8*)&buf[rrow + (((ks * 4 + g) ^ rx) * 8)];
            f16x8 af = relu8(xv + lp[ks]);
            #pragma unroll
            for (int fj = 0; fj < 4; ++fj)
                acc[fj] = __builtin_amdgcn_mfma_f32_16x16x32_f16(
                    af, bw[ks][fj], acc[fj], 0, 0, 0);
        }

        // layer 3: z[n] = sum_j relu(acc + b2[j]) * W3[j]; DPP row-reduce
        float pz[4];
        #pragma unroll
        for (int r = 0; r < 4; ++r) {
            float s = fmaxf(acc[0][r] + b2r[0], 0.f) * w3r[0]
                    + fmaxf(acc[1][r] + b2r[1], 0.f) * w3r[1]
                    + fmaxf(acc[2][r] + b2r[2], 0.f) * w3r[2]
                    + fmaxf(acc[3][r] + b2r[3], 0.f) * w3r[3];
            pz[r] = row16_sum(s);
        }
        if (c < 4) {
            float zv = (c == 0) ? pz[0] : (c == 1) ? pz[1] : (c == 2) ? pz[2] : pz[3];
            zdst[(size_t)mi * NVN + ch * 64 + wl * 16 + g * 4 + c] = zv;
        }
        __syncthreads();   // buf[ch&1] may be overwritten two iters later
    }
}

// -------------------------------------------------------------------------
// Kernel 4: per-(b,m) softmax over z + attn write + coords einsum.
// 512 blocks x 256 thr.
// -------------------------------------------------------------------------
__global__ __launch_bounds__(256) void softmax_coords(
    const float* __restrict__ zbuf, const float* __restrict__ vc,
    float* __restrict__ out_coords, float* __restrict__ out_attn)
{
    __shared__ float red[4];
    __shared__ float redc[3][4];

    const int tid = threadIdx.x;
    const int bm  = blockIdx.x;
    const int b   = bm >> 6;
    const int wid = tid >> 6, lane = tid & 63;

    float zloc[4];
    float mx = -INFINITY;
    #pragma unroll
    for (int k = 0; k < 4; ++k) {
        zloc[k] = zbuf[(size_t)bm * NVN + tid + k * 256];
        mx = fmaxf(mx, zloc[k]);
    }
    #pragma unroll
    for (int off = 32; off > 0; off >>= 1) mx = fmaxf(mx, __shfl_xor(mx, off));
    if (lane == 0) red[wid] = mx;
    __syncthreads();
    if (tid == 0)
        red[0] = fmaxf(fmaxf(red[0], red[1]), fmaxf(red[2], red[3]));
    __syncthreads();
    const float gmax = red[0];
    __syncthreads();

    float s = 0.f;
    #pragma unroll
    for (int k = 0; k < 4; ++k) {
        zloc[k] = expf(zloc[k] - gmax);
        s += zloc[k];
    }
    #pragma unroll
    for (int off = 32; off > 0; off >>= 1) s += __shfl_xor(s, off);
    if (lane == 0) red[wid] = s;
    __syncthreads();
    if (tid == 0) red[0] = red[0] + red[1] + red[2] + red[3];
    __syncthreads();
    const float inv = 1.f / red[0];

    float cx = 0.f, cy = 0.f, cz = 0.f;
    #pragma unroll
    for (int k = 0; k < 4; ++k) {
        int n = tid + k * 256;
        float a = zloc[k] * inv;
        out_attn[(size_t)bm * NVN + n] = a;
        const float* vcp = vc + (size_t)(b * NVN + n) * 3;
        cx += a * vcp[0];
        cy += a * vcp[1];
        cz += a * vcp[2];
    }
    #pragma unroll
    for (int off = 32; off > 0; off >>= 1) {
        cx += __shfl_xor(cx, off);
        cy += __shfl_xor(cy, off);
        cz += __shfl_xor(cz, off);
    }
    if (lane == 0) { redc[0][wid] = cx; redc[1][wid] = cy; redc[2][wid] = cz; }
    __syncthreads();
    if (tid == 0) {
        out_coords[bm * 3 + 0] = redc[0][0] + redc[0][1] + redc[0][2] + redc[0][3];
        out_coords[bm * 3 + 1] = redc[1][0] + redc[1][1] + redc[1][2] + redc[1][3];
        out_coords[bm * 3 + 2] = redc[2][0] + redc[2][1] + redc[2][2] + redc[2][3];
    }
}

// -------------------------------------------------------------------------
extern "C" void kernel_launch(void* const* d_in, const int* in_sizes, int n_in,
                              void* d_out, int out_size, void* d_ws, size_t ws_size,
                              hipStream_t stream)
{
    const float* VE = (const float*)d_in[0];   // [8192, 128]
    const float* vc = (const float*)d_in[1];   // [8192, 3]
    const float* LE = (const float*)d_in[2];   // [512, 128]
    const float* Wv = (const float*)d_in[6];
    const float* bv = (const float*)d_in[7];
    const float* Wl = (const float*)d_in[8];
    const float* bl = (const float*)d_in[9];
    const float* W1 = (const float*)d_in[10];
    const float* b1 = (const float*)d_in[11];
    const float* W2 = (const float*)d_in[12];
    const float* b2 = (const float*)d_in[13];
    const float* W3 = (const float*)d_in[14];
    // b3 cancels in softmax

    float* ws     = (float*)d_ws;
    float* Wc_v   = ws;                        // 16384 fp32
    float* Wc_l   = ws + 16384;
    float* bias_v = ws + 32768;                // 128
    float* bias_l = ws + 32896;                // 128
    f16*   v_hp   = (f16*)(ws + 33024);        // 8192*128 f16
    f16*   l_hp   = v_hp + (size_t)NB * NVN * H;  // 512*128 f16
    float* zbuf   = ws + 33024 + ((size_t)NB * NVN * H + 512 * H) / 2;  // 512*1024 fp32

    float* out_coords = (float*)d_out;         // [512, 3]
    float* out_attn   = out_coords + NB * MLIG * 3;

    combine_weights2<<<dim3(H, 2), 256, 0, stream>>>(
        Wv, bv, Wl, bl, W1, b1, Wc_v, Wc_l, bias_v, bias_l);

    project2<<<256 + 16, 256, 0, stream>>>(
        VE, LE, Wc_v, Wc_l, bias_v, bias_l, v_hp, l_hp);

    pair_mlp<<<512, 512, 0, stream>>>(
        v_hp, l_hp, W2, b2, W3, zbuf);

    softmax_coords<<<NB * MLIG, 256, 0, stream>>>(
        zbuf, vc, out_coords, out_attn);
}